// Round 14
// baseline (204.596 us; speedup 1.0000x reference)
//
#include <hip/hip_runtime.h>

#define BSZ 64
#define SEQ 512
#define HID 768
#define NK  21
#define NSEG 32        // segments per batch
#define SEGLEN 16      // steps per segment (NSEG*SEGLEN == SEQ)
#define PSTR 512       // padded matrix stride in shorts (rows padded to 24; 1 KB/matrix)

typedef short bf16x8 __attribute__((ext_vector_type(8)));
typedef float f32x4  __attribute__((ext_vector_type(4)));

__device__ __forceinline__ unsigned f2bf1(float x) {   // RNE fp32->bf16
    unsigned u = __float_as_uint(x);
    return (u + 0x7fffu + ((u >> 16) & 1u)) >> 16;
}
__device__ __forceinline__ unsigned f2bf_pk(float lo, float hi) {
    return f2bf1(lo) | (f2bf1(hi) << 16);
}

// unpack bf16 pair packed in a dword (memory order: low short = even index)
#define U16L(d) __uint_as_float(((unsigned)(d)) << 16)
#define U16H(d) __uint_as_float(((unsigned)(d)) & 0xffff0000u)

// ------- W pre-convert (blocks 0..95) + per-batch lengths (block 96) --------
__global__ __launch_bounds__(256) void wconv_len_kernel(
    const float* __restrict__ W, const int* __restrict__ mask,
    unsigned short* __restrict__ WT, int* __restrict__ Lbuf,
    float* __restrict__ out)
{
    if (blockIdx.x < 96) {
        const int idx = blockIdx.x * 256 + threadIdx.x;    // 0 .. 24575
        const int n = idx / HID;
        const int k = idx - n * HID;
        unsigned short v = 0;
        if (n < NK) v = (unsigned short)f2bf1(W[(size_t)k * NK + n]);
        WT[idx] = v;
    } else {
        const int tid = threadIdx.x;
        if (tid == 255) out[BSZ * SEQ * NK] = 0.f;         // nll accumulator
        const int b = tid >> 2, q = tid & 3;               // 4 threads per batch
        const int* msk = mask + b * SEQ + q * 128;
        int cnt = 0;
        for (int r = 0; r < 128; ++r) cnt += (msk[r] != 0);
        cnt += __shfl_xor(cnt, 1, 64);
        cnt += __shfl_xor(cnt, 2, 64);
        if (q == 0 && b < BSZ) Lbuf[b] = cnt;
    }
}

// ---------------- GEMM + bias (bf16 MFMA), SPLIT-K x2 ------------------------
// Grid 2048 x 128 thr (2 waves). Both waves share a 16-row M-tile; wave w
// covers K-chunks [12w, 12w+12). 4096 waves = 4/SIMD (was 2) for latency
// hiding on the A stream. Wave 1 partials via LDS, wave 0 combines+stores.
__global__ __launch_bounds__(128) void gemm_bias_kernel(
    const float* __restrict__ hidden, const unsigned short* __restrict__ WT,
    const float* __restrict__ bias, float* __restrict__ out)
{
    __shared__ float part0[16][16];                    // wave-1 partials, ntile 0
    __shared__ float part1[16][16];                    // ntile 1

    const int tid  = threadIdx.x;
    const int lane = tid & 63;
    const int wv   = tid >> 6;                         // K-half owner
    const int n    = lane & 15;
    const int quad = lane >> 4;

    const int arow = blockIdx.x * 16 + n;
    const float* ap = hidden + (size_t)arow * HID + wv * 384 + quad * 8;
    const bf16x8* bp0 = (const bf16x8*)(WT + (size_t)n * HID + wv * 384 + quad * 8);
    const bf16x8* bp1 = (const bf16x8*)(WT + (size_t)(16 + n) * HID + wv * 384 + quad * 8);

    f32x4 acc0 = {0.f, 0.f, 0.f, 0.f};
    f32x4 acc1 = {0.f, 0.f, 0.f, 0.f};

    // prefetch: A chunks 0,1; B chunk 0 (within this wave's 12-chunk half)
    float4 a0 = *(const float4*)(ap + 0);
    float4 a1 = *(const float4*)(ap + 4);
    float4 p0 = *(const float4*)(ap + 32);
    float4 p1 = *(const float4*)(ap + 36);
    bf16x8 B0 = bp0[0];
    bf16x8 B1 = bp1[0];

    #pragma unroll
    for (int c = 0; c < 12; ++c) {                     // 12 K-chunks per wave
        float4 q0, q1; bf16x8 Bn0, Bn1;
        if (c + 2 < 12) {                              // A depth-2
            q0 = *(const float4*)(ap + (c + 2) * 32);
            q1 = *(const float4*)(ap + (c + 2) * 32 + 4);
        }
        if (c + 1 < 12) {                              // B depth-1
            Bn0 = bp0[(c + 1) * 4];
            Bn1 = bp1[(c + 1) * 4];
        }
        union { bf16x8 v; unsigned u[4]; } af;
        af.u[0] = f2bf_pk(a0.x, a0.y);
        af.u[1] = f2bf_pk(a0.z, a0.w);
        af.u[2] = f2bf_pk(a1.x, a1.y);
        af.u[3] = f2bf_pk(a1.z, a1.w);

        acc0 = __builtin_amdgcn_mfma_f32_16x16x32_bf16(af.v, B0, acc0, 0, 0, 0);
        acc1 = __builtin_amdgcn_mfma_f32_16x16x32_bf16(af.v, B1, acc1, 0, 0, 0);

        a0 = p0; a1 = p1; p0 = q0; p1 = q1;
        B0 = Bn0; B1 = Bn1;
    }

    // C/D layout: col = n, row = quad*4 + r
    if (wv == 1) {
        #pragma unroll
        for (int r = 0; r < 4; ++r) {
            part0[quad * 4 + r][n] = acc0[r];
            part1[quad * 4 + r][n] = acc1[r];
        }
    }
    __syncthreads();

    if (wv == 0) {
        const float b0v = bias[n];
        const float b1v = (n < NK - 16) ? bias[16 + n] : 0.f;
        const int rbase = blockIdx.x * 16 + quad * 4;
        #pragma unroll
        for (int r = 0; r < 4; ++r) {
            float* op = out + (size_t)(rbase + r) * NK;
            op[n] = acc0[r] + part0[quad * 4 + r][n] + b0v;
            if (n < NK - 16)
                op[16 + n] = acc1[r] + part1[quad * 4 + r][n] + b1v;
        }
    }
}

// ---------------- CRF pre-pass — UNCHANGED from R13 --------------------------
#define EHI(u) __uint_as_float((u) & 0xffff0000u)
#define ELO(u) __uint_as_float((u) << 16)
__global__ __launch_bounds__(64, 2) void prepass_kernel(
    const float* __restrict__ logits, const float* __restrict__ trans,
    const int* __restrict__ Lbuf,
    unsigned short* __restrict__ Nrowb, unsigned short* __restrict__ Ncolb,
    float* __restrict__ rlog)
{
    const int bs   = blockIdx.x;                 // b*NSEG + s
    const int b    = bs >> 5;
    const int s    = bs & 31;
    const int lane = threadIdx.x;
    int g = lane / 21; if (g > 2) g = 2;         // lane 63 duplicates (20,2)
    int i = lane - g * 21; if (i > 20) i = 20;
    const int j0 = 7 * g;

    const int L = Lbuf[b];

    unsigned Epk[7][11];
    #pragma unroll
    for (int jl = 0; jl < 7; ++jl)
        #pragma unroll
        for (int p = 0; p < 11; ++p) {
            const float ehi = __expf(trans[(2 * p) * NK + j0 + jl]);
            const float elo = (2 * p + 1 < 21)
                            ? __expf(trans[(2 * p + 1) * NK + j0 + jl]) : 0.f;
            Epk[jl][p] = (f2bf1(ehi) << 16) | f2bf1(elo);
        }

    const float* lg = logits + (size_t)b * SEQ * NK;

    float P[7];
    float rl = 0.f;                              // segment C-sum + renorm logs
    const int t0 = s * SEGLEN + 1;

    if (t0 < L) {                                // P := M_{t0}
        const float C = lg[t0 * NK];
        rl = C;
        #pragma unroll
        for (int jl = 0; jl < 7; ++jl)
            P[jl] = __expf(trans[i * NK + j0 + jl])
                  * __expf(lg[t0 * NK + j0 + jl] - C);
    } else {                                     // identity
        #pragma unroll
        for (int jl = 0; jl < 7; ++jl) P[jl] = (i == j0 + jl) ? 1.f : 0.f;
    }

#define BPF(v, idx) __uint_as_float(__builtin_amdgcn_ds_bpermute((idx) * 4, __float_as_uint(v)))

    #pragma unroll
    for (int u = 1; u < SEGLEN; ++u) {
        const int t = t0 + u;
        if (t < L) {                             // wave-uniform branch
            float row[22];
            #pragma unroll
            for (int k = 0; k < 21; ++k)
                row[k] = BPF(P[k % 7], (k / 7) * 21 + i);
            row[21] = 0.f;

            const float C = lg[t * NK];
            rl += C;
            float X[7];
            #pragma unroll
            for (int jl = 0; jl < 7; ++jl)
                X[jl] = __expf(lg[t * NK + j0 + jl] - C);

            #pragma unroll
            for (int jl = 0; jl < 7; ++jl) {
                float s0 = 0.f, s1 = 0.f;
                #pragma unroll
                for (int p = 0; p < 11; ++p) {
                    const unsigned e = Epk[jl][p];
                    s0 = fmaf(row[2 * p    ], EHI(e), s0);
                    s1 = fmaf(row[2 * p + 1], ELO(e), s1);
                }
                P[jl] = (s0 + s1) * X[jl];
            }
            const float m = BPF(P[0], 0);        // entry [0][0]
            const float r = __builtin_amdgcn_rcpf(m);
            #pragma unroll
            for (int jl = 0; jl < 7; ++jl) P[jl] *= r;
            rl += __logf(m);
        }
    }
#undef BPF

    if (lane < 63) {                             // lane 63 is a duplicate
        unsigned short* nr = Nrowb + (size_t)bs * PSTR + i * 24 + j0;
        #pragma unroll
        for (int jl = 0; jl < 7; ++jl) nr[jl] = (unsigned short)f2bf1(P[jl]);
        unsigned short* nc = Ncolb + (size_t)bs * PSTR + i;
        #pragma unroll
        for (int jl = 0; jl < 7; ++jl)
            nc[(j0 + jl) * 24] = (unsigned short)f2bf1(P[jl]);
    }
    if (lane == 0) rlog[bs] = rl;
}

// ---------------- CRF scan — UNCHANGED from R13 ------------------------------
__global__ __launch_bounds__(128) void scan_kernel(
    const float* __restrict__ logits,
    const float* __restrict__ start_t,
    const float* __restrict__ trans,
    const float* __restrict__ end_t,
    const int* __restrict__ labels,
    const int* __restrict__ Lbuf,
    const unsigned short* __restrict__ Nrowb,
    const unsigned short* __restrict__ Ncolb,
    const float* __restrict__ rlog,
    float* __restrict__ out)
{
    __shared__ float comb[26];

    const int b    = blockIdx.x;
    const int tid  = threadIdx.x;
    const int lane = tid & 63;
    const int wid  = tid >> 6;                   // 0 = forward, 1 = backward

    const float* lg = logits + (size_t)b * SEQ * NK;
    const int* lab = labels + b * SEQ;
    const int L = Lbuf[b];

    {   // numerator partials over 128 threads
        float numacc = 0.f;
        for (int t = tid; t < L; t += 128) {
            if (t == 0) numacc += start_t[lab[0]] + lg[lab[0]];
            else        numacc += lg[t * NK + lab[t]] + trans[lab[t - 1] * NK + lab[t]];
        }
        if (tid == 0) numacc += end_t[lab[L - 1]];
        #pragma unroll
        for (int off = 32; off > 0; off >>= 1) numacc += __shfl_xor(numacc, off, 64);
        if (lane == 0) comb[22 + wid] = numacc;
    }

    float rls = (lane < 16) ? rlog[b * NSEG + wid * 16 + lane] : 0.f;
    #pragma unroll
    for (int off = 32; off > 0; off >>= 1) rls += __shfl_xor(rls, off, 64);

    const int jj = (lane < NK) ? lane : NK - 1;

#define RL(v, k) __uint_as_float(__builtin_amdgcn_readlane(__float_as_uint(v), k))
#define PMV(vv, c0, c1, c2, outv) do {                                        \
    float s0 = RL(vv, 0) * U16L(c0.x);                                        \
    float s1 = RL(vv, 1) * U16H(c0.x);                                        \
    float s2 = RL(vv, 2) * U16L(c0.y);                                        \
    s0 = fmaf(RL(vv,  3), U16H(c0.y), s0); s1 = fmaf(RL(vv,  4), U16L(c0.z), s1); \
    s2 = fmaf(RL(vv,  5), U16H(c0.z), s2); s0 = fmaf(RL(vv,  6), U16L(c0.w), s0); \
    s1 = fmaf(RL(vv,  7), U16H(c0.w), s1); s2 = fmaf(RL(vv,  8), U16L(c1.x), s2); \
    s0 = fmaf(RL(vv,  9), U16H(c1.x), s0); s1 = fmaf(RL(vv, 10), U16L(c1.y), s1); \
    s2 = fmaf(RL(vv, 11), U16H(c1.y), s2); s0 = fmaf(RL(vv, 12), U16L(c1.z), s0); \
    s1 = fmaf(RL(vv, 13), U16H(c1.z), s1); s2 = fmaf(RL(vv, 14), U16L(c1.w), s2); \
    s0 = fmaf(RL(vv, 15), U16H(c1.w), s0); s1 = fmaf(RL(vv, 16), U16L(c2.x), s1); \
    s2 = fmaf(RL(vv, 17), U16H(c2.x), s2); s0 = fmaf(RL(vv, 18), U16L(c2.y), s0); \
    s1 = fmaf(RL(vv, 19), U16H(c2.y), s1); s2 = fmaf(RL(vv, 20), U16L(c2.z), s2); \
    outv = (s0 + s1) + s2;                                                    \
} while (0)

    float a, Orenorm = 0.f;
    int4 c0, c1, c2, n0, n1, n2;

    if (wid == 0) {
        a = __expf(start_t[jj]) * __expf(lg[jj] - lg[0]);   // alpha_0

        const char* base = (const char*)(Ncolb + (size_t)b * NSEG * PSTR) + jj * 48;
        c0 = *(const int4*)(base);
        c1 = *(const int4*)(base + 16);
        c2 = *(const int4*)(base + 32);
        for (int s = 0; s < 16; ++s) {
            if (s < 15) {
                const char* p = base + (size_t)(s + 1) * (PSTR * 2);
                n0 = *(const int4*)(p);
                n1 = *(const int4*)(p + 16);
                n2 = *(const int4*)(p + 32);
            }
            float nv; PMV(a, c0, c1, c2, nv); a = nv;
            const float m = __uint_as_float(
                __builtin_amdgcn_readfirstlane(__float_as_uint(a)));
            a *= __builtin_amdgcn_rcpf(m);
            Orenorm += __logf(m);
            c0 = n0; c1 = n1; c2 = n2;
        }
    } else {
        a = __expf(end_t[jj]);                   // beta at t = L-1

        const char* base = (const char*)(Nrowb + (size_t)b * NSEG * PSTR) + jj * 48;
        {
            const char* p = base + (size_t)31 * (PSTR * 2);
            c0 = *(const int4*)(p);
            c1 = *(const int4*)(p + 16);
            c2 = *(const int4*)(p + 32);
        }
        for (int s = 31; s >= 16; --s) {
            if (s > 16) {
                const char* p = base + (size_t)(s - 1) * (PSTR * 2);
                n0 = *(const int4*)(p);
                n1 = *(const int4*)(p + 16);
                n2 = *(const int4*)(p + 32);
            }
            float nv; PMV(a, c0, c1, c2, nv); a = nv;
            const float m = __uint_as_float(
                __builtin_amdgcn_readfirstlane(__float_as_uint(a)));
            a *= __builtin_amdgcn_rcpf(m);
            Orenorm += __logf(m);
            c0 = n0; c1 = n1; c2 = n2;
        }
    }
#undef RL
#undef PMV

    if (wid == 1) {
        if (lane < NK) comb[lane] = a;           // beta_m
        if (lane == 0) comb[21] = Orenorm + rls;
    }
    __syncthreads();

    if (wid == 0) {
        float val = (lane < NK) ? a * comb[lane] : 0.f;
        #pragma unroll
        for (int off = 32; off > 0; off >>= 1) val += __shfl_xor(val, off, 64);
        if (lane == 0) {
            const float OF  = Orenorm + rls + lg[0];
            const float num = comb[22] + comb[23];
            atomicAdd(out + BSZ * SEQ * NK, OF + comb[21] + __logf(val) - num);
        }
    }
}

extern "C" void kernel_launch(void* const* d_in, const int* in_sizes, int n_in,
                              void* d_out, int out_size, void* d_ws, size_t ws_size,
                              hipStream_t stream)
{
    const float* hidden  = (const float*)d_in[0];
    const float* W       = (const float*)d_in[1];
    const float* bias    = (const float*)d_in[2];
    const float* start_t = (const float*)d_in[3];
    const float* trans   = (const float*)d_in[4];
    const float* end_t   = (const float*)d_in[5];
    const int*   labels  = (const int*)d_in[6];
    const int*   mask    = (const int*)d_in[7];
    float* out = (float*)d_out;

    char* ws = (char*)d_ws;
    unsigned short* WT    = (unsigned short*)ws;               // 48 KB
    int*            Lbuf  = (int*)(ws + 65536);                // 64 i
    float*          rlog  = (float*)(ws + 69632);              // 2048 f
    unsigned short* Nrowb = (unsigned short*)(ws + 131072);    // 2048*512 bf16 = 2 MB
    unsigned short* Ncolb = (unsigned short*)(ws + 131072 + 2 * 1024 * 1024);

    wconv_len_kernel<<<97, 256, 0, stream>>>(W, mask, WT, Lbuf, out);
    gemm_bias_kernel<<<(BSZ * SEQ) / 16, 128, 0, stream>>>(hidden, WT, bias, out);
    prepass_kernel<<<BSZ * NSEG, 64, 0, stream>>>(out, trans, Lbuf, Nrowb, Ncolb, rlog);
    scan_kernel<<<BSZ, 128, 0, stream>>>(out, start_t, trans, end_t, labels, Lbuf,
                                         Nrowb, Ncolb, rlog, out);
}